// Round 4
// baseline (396.817 us; speedup 1.0000x reference)
//
#include <hip/hip_runtime.h>
#include <stdint.h>

typedef unsigned long long u64;
typedef unsigned short u16;
typedef float nfloat4 __attribute__((ext_vector_type(4)));  // native vec for nt-store

#define LQ   4096
#define BQ   8
#define KNB  16
#define TPB  512
#define QPB  64                  // queries per block, 8 lanes each
#define BPB  (LQ / QPB)          // 64 blocks per batch

// u32 compare-exchange (full-rate v_min_u32/v_max_u32)
__device__ __forceinline__ void ceu(uint32_t &a, uint32_t &b) {
    const uint32_t mn = a < b ? a : b;
    const uint32_t mx = a < b ? b : a;
    a = mn; b = mx;
}
// f64 compare-exchange (exact 44-bit keys as positive denormals)
__device__ __forceinline__ void ced(double &a, double &b) {
    const double mn = __builtin_fmin(a, b);
    const double mx = __builtin_fmax(a, b);
    a = mn; b = mx;
}
// bit-exact vs reference: no FMA, sum order (x^2+y^2)+z^2
__device__ __forceinline__ float dist2(float mx, float my, float mz,
                                       float px, float py, float pz) {
    const float dx = __fsub_rn(mx, px);
    const float dy = __fsub_rn(my, py);
    const float dz = __fsub_rn(mz, pz);
    return __fadd_rn(__fadd_rn(__fmul_rn(dx, dx), __fmul_rn(dy, dy)),
                     __fmul_rn(dz, dz));
}

// ---------------- pre-kernel: per-batch bitonic sort by x ----------------
__global__ __launch_bounds__(512) void sort_kernel(
    const float4* __restrict__ frame4,
    float* __restrict__ wx, float* __restrict__ wy,
    float* __restrict__ wz, int* __restrict__ wperm)
{
    __shared__ u64 SK[LQ];               // 32 KB
    const int b   = blockIdx.x;
    const int tid = threadIdx.x;
    const float4* fb = frame4 + (size_t)b * LQ * 3;

    for (int j = tid; j < LQ; j += 512) {
        const uint32_t bits = __float_as_uint(fb[j * 3].x);
        // monotone map f32 -> u32 (handles negatives): ascending mk <=> ascending x
        const uint32_t mk = (bits & 0x80000000u) ? ~bits : (bits | 0x80000000u);
        SK[j] = ((u64)mk << 32) | (unsigned)j;
    }
    __syncthreads();
    for (int k = 2; k <= LQ; k <<= 1) {
        for (int g = k >> 1; g >= 1; g >>= 1) {
            for (int t = tid; t < LQ / 2; t += 512) {
                const int i  = ((t & ~(g - 1)) << 1) | (t & (g - 1));
                const int j2 = i | g;
                const bool up = ((i & k) == 0);
                const u64 a = SK[i], c = SK[j2];
                if ((a > c) == up) { SK[i] = c; SK[j2] = a; }
            }
            __syncthreads();
        }
    }
    for (int p = tid; p < LQ; p += 512) {
        const int orig = (int)(SK[p] & 0xFFFu);
        const float4 v = fb[orig * 3];
        const size_t o = (size_t)b * LQ + p;
        wx[o] = v.x; wy[o] = v.y; wz[o] = v.z; wperm[o] = orig;
    }
}

// ---------------- main fused kernel (x-window pruned scan) ----------------
// Scan key: (f32 dist bits truncated to top 20) << 12 | sorted_pos.  Per-lane
// top-16 over the scanned window; union keep-128 -> top-32 superset; exact
// re-rank with ((u64)d_bits << 12) | ORIG index (reference tie-break).
// Window stop is EXACT: remaining points have computed d^2 >= fl(dx_boundary^2);
// stop when that strictly exceeds an upper bound (+16 ulp margin) on the
// query's current 16th-smallest distance.

__global__ __launch_bounds__(TPB) void knn_fused_kernel(
    const float4* __restrict__ frame4,   // (B, L, 3) float4 view of (B,L,4,3)
    const float4* __restrict__ attr4,    // (B, L, 32) float4 view of (B,L,128)
    const float* __restrict__ wx, const float* __restrict__ wy,
    const float* __restrict__ wz, const int* __restrict__ wperm,
    float* __restrict__ out_e,           // (B, L, 16, 3)
    nfloat4* __restrict__ outg4)         // (B, L, 16, 32) float4
{
    __shared__ float xs[LQ], ys[LQ], zs[LQ];   // 48 KB sorted coords
    __shared__ u16 perm_lds[LQ];               // 8 KB sorted_pos -> orig
    __shared__ u16 inv_lds[LQ];                // 8 KB orig -> sorted_pos
    __shared__ u16 surv[QPB][32];              // 4 KB per-query top-32 sorted_pos
    __shared__ int nbrs[QPB][KNB];             // 4 KB final neighbor orig idx
    // total 72 KB -> 2 blocks/CU

    const int b    = blockIdx.x >> 6;          // 64 blocks per batch
    const int qblk = blockIdx.x & (BPB - 1);
    const int tid  = threadIdx.x;

    const float4* fb = frame4 + (size_t)b * LQ * 3;
    {
        const float* bx = wx + (size_t)b * LQ;
        const float* by = wy + (size_t)b * LQ;
        const float* bz = wz + (size_t)b * LQ;
        const int*   bp = wperm + (size_t)b * LQ;
        for (int j = tid; j < LQ; j += TPB) {
            xs[j] = bx[j]; ys[j] = by[j]; zs[j] = bz[j];
            const int pm = bp[j];
            perm_lds[j] = (u16)pm;
            inv_lds[pm] = (u16)j;
        }
    }
    __syncthreads();   // only barrier: waves independent afterwards

    const int qloc = tid >> 3;           // 0..63 (sorted-position slot)
    const int h    = tid & 7;            // sub-stream within query
    const int wv   = tid >> 6;           // wave 0..7
    const int l    = qblk * QPB + qloc;  // sorted position of my query
    const float mx = xs[l], my = ys[l], mz = zs[l];
    const float xq_lo = xs[qblk * QPB + wv * 8];
    const float xq_hi = xs[qblk * QPB + wv * 8 + 7];

    uint32_t R[16];
#pragma unroll
    for (int i = 0; i < 16; ++i) R[i] = 0xFFFFFFFFu;

    const int A = qblk * QPB;            // 64-aligned window seed
    int lo = A, hi = A;
    bool doneR = false;
    bool doneL = (lo <= 0);

#pragma unroll 1
    while (!(doneR && doneL)) {
        // ---- uniform side pick: expand nearer boundary ----
        int base;
        {
            bool goRight;
            if (doneR) goRight = false;
            else if (doneL) goRight = true;
            else {
                const float dR = __fsub_rn(xs[hi], xq_hi);
                const float dL = __fsub_rn(xq_lo, xs[lo - 1]);
                goRight = !(dR > dL);
            }
            if (goRight) { base = hi; hi += 64; }
            else         { lo -= 64; base = lo; }
        }
        // ---- 8 candidates per lane from group [base, base+64) ----
        uint32_t K[8];
#pragma unroll
        for (int s = 0; s < 8; ++s) {
            const int pos = base + s * 8 + h;
            const int pp  = pos < 0 ? 0 : pos;
            const float dx = __fsub_rn(mx, xs[pp]);
            const float dy = __fsub_rn(my, ys[pp]);
            const float dz = __fsub_rn(mz, zs[pp]);
            const float d  = __fmaf_rn(dz, dz, __fmaf_rn(dy, dy, __fmul_rn(dx, dx)));
            const uint32_t key = (__float_as_uint(d) & 0xFFFFF000u) | (unsigned)pos;
            K[s] = (pos >= 0) ? key : 0xFFFFFFFFu;
        }
        // Batcher odd-even mergesort-8 (19 comparators), ascending
        ceu(K[0],K[1]); ceu(K[2],K[3]); ceu(K[4],K[5]); ceu(K[6],K[7]);
        ceu(K[0],K[2]); ceu(K[1],K[3]); ceu(K[4],K[6]); ceu(K[5],K[7]);
        ceu(K[1],K[2]); ceu(K[5],K[6]);
        ceu(K[0],K[4]); ceu(K[1],K[5]); ceu(K[2],K[6]); ceu(K[3],K[7]);
        ceu(K[2],K[4]); ceu(K[3],K[5]);
        ceu(K[1],K[2]); ceu(K[3],K[4]); ceu(K[5],K[6]);
        // bottom-16 of (R asc-16 ∪ K asc-8): min-layer then bitonic merge-16
#pragma unroll
        for (int t = 0; t < 8; ++t) {
            const uint32_t x = R[8 + t], y = K[7 - t];
            R[8 + t] = x < y ? x : y;
        }
#pragma unroll
        for (int g = 8; g >= 1; g >>= 1)
#pragma unroll
            for (int i = 0; i < 16; ++i)
                if ((i & g) == 0) ceu(R[i], R[i + g]);

        // ---- per-query upper bound on current 16th distance ----
        uint32_t ub = R[15] | 0xFFFu;
        { uint32_t t;
          t = __shfl_xor(ub, 1, 64); ub = ub < t ? ub : t;
          t = __shfl_xor(ub, 2, 64); ub = ub < t ? ub : t;
          t = __shfl_xor(ub, 4, 64); ub = ub < t ? ub : t; }
        uint32_t ubb = (ub & 0xFFFFF000u) | 0xFFFu;     // bucket upper (dist bits<<12 space... )
        ubb = ubb >> 12;                                 // f32-bit upper of 16th dist
        ubb = (ubb << 12) | 0xFFFu;                      // restore 32-bit f32 pattern upper
        ubb = (ubb > 0xFFFFFFEFu) ? 0xFFFFFFFFu : ubb + 16u;  // +16 ulp FMA margin

        // ---- exact stop checks (strict >) ----
        if (!doneR) {
            if (hi >= LQ) doneR = true;
            else {
                const float dxm = __fsub_rn(xs[hi], mx);
                const bool st = (dxm > 0.f) &&
                                (__float_as_uint(__fmul_rn(dxm, dxm)) > ubb);
                if (__all(st)) doneR = true;
            }
        }
        if (!doneL) {
            if (lo <= 0) doneL = true;
            else {
                const float dxm = __fsub_rn(mx, xs[lo - 1]);
                const bool st = (dxm > 0.f) &&
                                (__float_as_uint(__fmul_rn(dxm, dxm)) > ubb);
                if (__all(st)) doneL = true;
            }
        }
    }

    // ---- distributed cross-lane merge over the query's 8 lanes, keeping ALL
    // 128 elements: after this, position p = h*16+i is fully sorted ascending.
    {
        uint32_t P[16];
#pragma unroll
        for (int i = 0; i < 16; ++i) P[i] = __shfl_xor(R[i], 1, 64);
        const bool lo1 = (h & 1) == 0;
#pragma unroll
        for (int i = 0; i < 16; ++i) {
            const uint32_t o = P[15 - i];
            R[i] = lo1 ? (R[i] < o ? R[i] : o) : (R[i] > o ? R[i] : o);
        }
#pragma unroll
        for (int g = 8; g >= 1; g >>= 1)
#pragma unroll
            for (int i = 0; i < 16; ++i)
                if ((i & g) == 0) ceu(R[i], R[i + g]);
    }
    {
        uint32_t P[16];
#pragma unroll
        for (int i = 0; i < 16; ++i) P[i] = __shfl_xor(R[i], 3, 64);
        const bool lo2 = (h & 2) == 0;
#pragma unroll
        for (int i = 0; i < 16; ++i) {
            const uint32_t o = P[15 - i];
            R[i] = lo2 ? (R[i] < o ? R[i] : o) : (R[i] > o ? R[i] : o);
        }
#pragma unroll
        for (int i = 0; i < 16; ++i) P[i] = __shfl_xor(R[i], 1, 64);
        const bool lo1 = (h & 1) == 0;
#pragma unroll
        for (int i = 0; i < 16; ++i) {
            const uint32_t o = P[i];
            R[i] = lo1 ? (R[i] < o ? R[i] : o) : (R[i] > o ? R[i] : o);
        }
#pragma unroll
        for (int g = 8; g >= 1; g >>= 1)
#pragma unroll
            for (int i = 0; i < 16; ++i)
                if ((i & g) == 0) ceu(R[i], R[i + g]);
    }
    {
        uint32_t P[16];
#pragma unroll
        for (int i = 0; i < 16; ++i) P[i] = __shfl_xor(R[i], 7, 64);
        const bool lo4 = (h & 4) == 0;
#pragma unroll
        for (int i = 0; i < 16; ++i) {
            const uint32_t o = P[15 - i];
            R[i] = lo4 ? (R[i] < o ? R[i] : o) : (R[i] > o ? R[i] : o);
        }
#pragma unroll
        for (int i = 0; i < 16; ++i) P[i] = __shfl_xor(R[i], 2, 64);
        const bool lo2 = (h & 2) == 0;
#pragma unroll
        for (int i = 0; i < 16; ++i) {
            const uint32_t o = P[i];
            R[i] = lo2 ? (R[i] < o ? R[i] : o) : (R[i] > o ? R[i] : o);
        }
#pragma unroll
        for (int i = 0; i < 16; ++i) P[i] = __shfl_xor(R[i], 1, 64);
        const bool lo1 = (h & 1) == 0;
#pragma unroll
        for (int i = 0; i < 16; ++i) {
            const uint32_t o = P[i];
            R[i] = lo1 ? (R[i] < o ? R[i] : o) : (R[i] > o ? R[i] : o);
        }
#pragma unroll
        for (int g = 8; g >= 1; g >>= 1)
#pragma unroll
            for (int i = 0; i < 16; ++i)
                if ((i & g) == 0) ceu(R[i], R[i + g]);
    }

    // lanes 0,1 hold the query's top-32 keys -> publish sorted positions
    if (h < 2) {
#pragma unroll
        for (int i = 0; i < 16; ++i)
            surv[qloc][h * 16 + i] = (u16)(R[i] & 0xFFFu);
    }

    // ---- exact re-rank of the 32 survivors: key = d_bits<<12 | ORIG idx ----
    double kd[4];
#pragma unroll
    for (int s = 0; s < 4; ++s) {
        const int sp = surv[qloc][h * 4 + s];
        const float d = dist2(mx, my, mz, xs[sp], ys[sp], zs[sp]);
        kd[s] = __builtin_bit_cast(double,
                 ((u64)__float_as_uint(d) << 12) | (unsigned)perm_lds[sp]);
    }
    ced(kd[0],kd[1]); ced(kd[2],kd[3]); ced(kd[0],kd[2]); ced(kd[1],kd[3]); ced(kd[1],kd[2]);
    {
        double P[4];
#pragma unroll
        for (int s = 0; s < 4; ++s) P[s] = __shfl_xor(kd[s], 1, 64);
        const bool lo1 = (h & 1) == 0;
#pragma unroll
        for (int s = 0; s < 4; ++s) {
            const double o = P[3 - s];
            kd[s] = lo1 ? __builtin_fmin(kd[s], o) : __builtin_fmax(kd[s], o);
        }
        ced(kd[0],kd[2]); ced(kd[1],kd[3]); ced(kd[0],kd[1]); ced(kd[2],kd[3]);
    }
    {
        double P[4];
#pragma unroll
        for (int s = 0; s < 4; ++s) P[s] = __shfl_xor(kd[s], 3, 64);
        const bool lo2 = (h & 2) == 0;
#pragma unroll
        for (int s = 0; s < 4; ++s) {
            const double o = P[3 - s];
            kd[s] = lo2 ? __builtin_fmin(kd[s], o) : __builtin_fmax(kd[s], o);
        }
#pragma unroll
        for (int s = 0; s < 4; ++s) P[s] = __shfl_xor(kd[s], 1, 64);
        const bool lo1 = (h & 1) == 0;
#pragma unroll
        for (int s = 0; s < 4; ++s) {
            const double o = P[s];
            kd[s] = lo1 ? __builtin_fmin(kd[s], o) : __builtin_fmax(kd[s], o);
        }
        ced(kd[0],kd[2]); ced(kd[1],kd[3]); ced(kd[0],kd[1]); ced(kd[2],kd[3]);
    }
    {
        double P[4];
#pragma unroll
        for (int s = 0; s < 4; ++s) P[s] = __shfl_xor(kd[s], 7, 64);
        const bool lo4 = (h & 4) == 0;
#pragma unroll
        for (int s = 0; s < 4; ++s) {
            const double o = P[3 - s];
            kd[s] = lo4 ? __builtin_fmin(kd[s], o) : __builtin_fmax(kd[s], o);
        }
#pragma unroll
        for (int s = 0; s < 4; ++s) P[s] = __shfl_xor(kd[s], 2, 64);
        const bool lo2 = (h & 2) == 0;
#pragma unroll
        for (int s = 0; s < 4; ++s) {
            const double o = P[s];
            kd[s] = lo2 ? __builtin_fmin(kd[s], o) : __builtin_fmax(kd[s], o);
        }
#pragma unroll
        for (int s = 0; s < 4; ++s) P[s] = __shfl_xor(kd[s], 1, 64);
        const bool lo1 = (h & 1) == 0;
#pragma unroll
        for (int s = 0; s < 4; ++s) {
            const double o = P[s];
            kd[s] = lo1 ? __builtin_fmin(kd[s], o) : __builtin_fmax(kd[s], o);
        }
        ced(kd[0],kd[2]); ced(kd[1],kd[3]); ced(kd[0],kd[1]); ced(kd[2],kd[3]);
    }

    // lanes h<4 hold final top-16 (position h*4+s): epilogue
    const int ql_orig = perm_lds[l];
    const size_t gq = (size_t)b * LQ + (size_t)ql_orig;
    if (h < 4) {
        const float4 f0 = fb[ql_orig * 3 + 0];
        const float4 f1 = fb[ql_orig * 3 + 1];
        const float4 f2 = fb[ql_orig * 3 + 2];
        const float R00 = f0.w, R01 = f1.x, R02 = f1.y;
        const float R10 = f1.z, R11 = f1.w, R12 = f2.x;
        const float R20 = f2.y, R21 = f2.z, R22 = f2.w;
        float e[12];
#pragma unroll
        for (int s = 0; s < 4; ++s) {
            const u64 bits = __builtin_bit_cast(u64, kd[s]);
            const int jo = (int)(bits & 0xFFFu);      // ORIG neighbor index
            nbrs[qloc][h * 4 + s] = jo;
            const int sp = inv_lds[jo];               // coords via sorted pos
            const float dx = xs[sp] - mx;             // delta = nbr - center
            const float dy = ys[sp] - my;
            const float dz = zs[sp] - mz;
            e[s * 3 + 0] = dx * R00 + dy * R10 + dz * R20;
            e[s * 3 + 1] = dx * R01 + dy * R11 + dz * R21;
            e[s * 3 + 2] = dx * R02 + dy * R12 + dz * R22;
        }
        float4* eo = (float4*)(out_e + gq * 48 + h * 12);
        float4 v0 = {e[0], e[1], e[2],  e[3]};
        float4 v1 = {e[4], e[5], e[6],  e[7]};
        float4 v2 = {e[8], e[9], e[10], e[11]};
        eo[0] = v0; eo[1] = v1; eo[2] = v2;
    }

    // ---- fused gather (per wave: its 8 queries x 16 nbrs x 32 float4) ----
    const float4* ab = attr4 + (((size_t)b) << 12) * 32;
    const int lane = tid & 63;
    const int qbase = qblk * QPB + wv * 8;
#pragma unroll 4
    for (int it = 0; it < 64; ++it) {
        const int idx = it * 64 + lane;      // 0..4095
        const int qw  = idx >> 9;            // 0..7 within-wave query
        const int r   = idx & 511;
        const int k   = r >> 5, d4 = r & 31;
        const int nb  = nbrs[wv * 8 + qw][k];
        const int qo  = perm_lds[qbase + qw];
        const float4 v = ab[(size_t)nb * 32 + d4];
        nfloat4 nv = {v.x, v.y, v.z, v.w};
        __builtin_nontemporal_store(nv,
            &outg4[((size_t)b * LQ + (size_t)qo) * 512 + r]);
    }
}

extern "C" void kernel_launch(void* const* d_in, const int* in_sizes, int n_in,
                              void* d_out, int out_size, void* d_ws, size_t ws_size,
                              hipStream_t stream)
{
    const float* frame = (const float*)d_in[0];   // (8,4096,4,3) f32
    const float* attr  = (const float*)d_in[1];   // (8,4096,128) f32
    float* out = (float*)d_out;                   // euclidian ++ gathered

    float* wxp = (float*)d_ws;                    // sorted x   (8*4096)
    float* wyp = wxp + BQ * LQ;                   // sorted y
    float* wzp = wyp + BQ * LQ;                   // sorted z
    int*   wpp = (int*)(wzp + BQ * LQ);           // perm (orig idx)

    sort_kernel<<<BQ, 512, 0, stream>>>((const float4*)frame, wxp, wyp, wzp, wpp);

    nfloat4* outg4 = (nfloat4*)(out + (size_t)BQ * LQ * KNB * 3);
    knn_fused_kernel<<<BQ * BPB, TPB, 0, stream>>>(
        (const float4*)frame, (const float4*)attr, wxp, wyp, wzp, wpp,
        out, outg4);
}

// Round 5
// 372.459 us; speedup vs baseline: 1.0654x; 1.0654x over previous
//
#include <hip/hip_runtime.h>
#include <stdint.h>

typedef unsigned long long u64;
typedef unsigned short u16;
typedef float nfloat4 __attribute__((ext_vector_type(4)));  // native vec for nt-store

#define LQ   4096
#define BQ   8
#define KNB  16
#define TPB  512
#define QPB  64                  // queries per block, 8 lanes each
#define BPB  (LQ / QPB)          // 64 blocks per batch

// u32 compare-exchange (full-rate v_min_u32/v_max_u32)
__device__ __forceinline__ void ceu(uint32_t &a, uint32_t &b) {
    const uint32_t mn = a < b ? a : b;
    const uint32_t mx = a < b ? b : a;
    a = mn; b = mx;
}
// f64 compare-exchange (exact 44-bit keys as positive denormals)
__device__ __forceinline__ void ced(double &a, double &b) {
    const double mn = __builtin_fmin(a, b);
    const double mx = __builtin_fmax(a, b);
    a = mn; b = mx;
}
// bit-exact vs reference: no FMA, sum order (x^2+y^2)+z^2
__device__ __forceinline__ float dist2(float mx, float my, float mz,
                                       float px, float py, float pz) {
    const float dx = __fsub_rn(mx, px);
    const float dy = __fsub_rn(my, py);
    const float dz = __fsub_rn(mz, pz);
    return __fadd_rn(__fadd_rn(__fmul_rn(dx, dx), __fmul_rn(dy, dy)),
                     __fmul_rn(dz, dz));
}

// ---------------- pre-kernel: per-batch bitonic sort by x ----------------
__global__ __launch_bounds__(512) void sort_kernel(
    const float4* __restrict__ frame4,
    float* __restrict__ wx, float* __restrict__ wy,
    float* __restrict__ wz, int* __restrict__ wperm)
{
    __shared__ u64 SK[LQ];               // 32 KB
    const int b   = blockIdx.x;
    const int tid = threadIdx.x;
    const float4* fb = frame4 + (size_t)b * LQ * 3;

    for (int j = tid; j < LQ; j += 512) {
        const uint32_t bits = __float_as_uint(fb[j * 3].x);
        // monotone map f32 -> u32 (handles negatives): ascending mk <=> ascending x
        const uint32_t mk = (bits & 0x80000000u) ? ~bits : (bits | 0x80000000u);
        SK[j] = ((u64)mk << 32) | (unsigned)j;
    }
    __syncthreads();
    for (int k = 2; k <= LQ; k <<= 1) {
        for (int g = k >> 1; g >= 1; g >>= 1) {
            for (int t = tid; t < LQ / 2; t += 512) {
                const int i  = ((t & ~(g - 1)) << 1) | (t & (g - 1));
                const int j2 = i | g;
                const bool up = ((i & k) == 0);
                const u64 a = SK[i], c = SK[j2];
                if ((a > c) == up) { SK[i] = c; SK[j2] = a; }
            }
            __syncthreads();
        }
    }
    for (int p = tid; p < LQ; p += 512) {
        const int orig = (int)(SK[p] & 0xFFFu);
        const float4 v = fb[orig * 3];
        const size_t o = (size_t)b * LQ + p;
        wx[o] = v.x; wy[o] = v.y; wz[o] = v.z; wperm[o] = orig;
    }
}

// ---------------- main fused kernel (precomputed x-window scan) ----------------
// Seed 192 x-neighbors -> exact seed-union 16th key (upper bound on final d16,
// since rank within a subset <= rank within the superset). Window = all pos with
// |x - xq| <= sqrt(ub)+8ulp (conservative: excluded points have fl(dx^2) > ubb,
// bucket-upper +16 ulp margin, harness-verified in round 4). Then a static-step
// scan over the window (seed range skipped to avoid duplicates) with ZERO
// per-group ballots/reductions -> pipelinable like the round-3 loop.

__global__ __launch_bounds__(TPB) void knn_fused_kernel(
    const float4* __restrict__ frame4,   // (B, L, 3) float4 view of (B,L,4,3)
    const float4* __restrict__ attr4,    // (B, L, 32) float4 view of (B,L,128)
    const float* __restrict__ wx, const float* __restrict__ wy,
    const float* __restrict__ wz, const int* __restrict__ wperm,
    float* __restrict__ out_e,           // (B, L, 16, 3)
    nfloat4* __restrict__ outg4)         // (B, L, 16, 32) float4
{
    __shared__ float xs[LQ], ys[LQ], zs[LQ];   // 48 KB sorted coords
    __shared__ u16 perm_lds[LQ];               // 8 KB sorted_pos -> orig
    __shared__ u16 inv_lds[LQ];                // 8 KB orig -> sorted_pos
    __shared__ u16 surv[QPB][32];              // 4 KB per-query top-32 sorted_pos
    __shared__ int nbrs[QPB][KNB];             // 4 KB final neighbor orig idx
    // total 72 KB -> 2 blocks/CU

    const int b    = blockIdx.x >> 6;          // 64 blocks per batch
    const int qblk = blockIdx.x & (BPB - 1);
    const int tid  = threadIdx.x;

    const float4* fb = frame4 + (size_t)b * LQ * 3;
    {
        const float* bx = wx + (size_t)b * LQ;
        const float* by = wy + (size_t)b * LQ;
        const float* bz = wz + (size_t)b * LQ;
        const int*   bp = wperm + (size_t)b * LQ;
        for (int j = tid; j < LQ; j += TPB) {
            xs[j] = bx[j]; ys[j] = by[j]; zs[j] = bz[j];
            const int pm = bp[j];
            perm_lds[j] = (u16)pm;
            inv_lds[pm] = (u16)j;
        }
    }
    __syncthreads();   // only barrier: waves independent afterwards

    const int qloc = tid >> 3;           // 0..63 (sorted-position slot)
    const int h    = tid & 7;            // sub-stream within query
    const int wv   = tid >> 6;           // wave 0..7
    const int l    = qblk * QPB + qloc;  // sorted position of my query
    const float mx = xs[l], my = ys[l], mz = zs[l];

    uint32_t R[16];
#pragma unroll
    for (int i = 0; i < 16; ++i) R[i] = 0xFFFFFFFFu;

    // ---- scan one 64-candidate group into per-lane top-16 R ----
    auto scan_group = [&](const int base) {
        uint32_t K[8];
#pragma unroll
        for (int s = 0; s < 8; ++s) {
            const int pos = base + s * 8 + h;
            const float dx = __fsub_rn(mx, xs[pos]);
            const float dy = __fsub_rn(my, ys[pos]);
            const float dz = __fsub_rn(mz, zs[pos]);
            const float d  = __fmaf_rn(dz, dz, __fmaf_rn(dy, dy, __fmul_rn(dx, dx)));
            K[s] = (__float_as_uint(d) & 0xFFFFF000u) | (unsigned)pos;
        }
        // Batcher odd-even mergesort-8 (19 comparators), ascending
        ceu(K[0],K[1]); ceu(K[2],K[3]); ceu(K[4],K[5]); ceu(K[6],K[7]);
        ceu(K[0],K[2]); ceu(K[1],K[3]); ceu(K[4],K[6]); ceu(K[5],K[7]);
        ceu(K[1],K[2]); ceu(K[5],K[6]);
        ceu(K[0],K[4]); ceu(K[1],K[5]); ceu(K[2],K[6]); ceu(K[3],K[7]);
        ceu(K[2],K[4]); ceu(K[3],K[5]);
        ceu(K[1],K[2]); ceu(K[3],K[4]); ceu(K[5],K[6]);
        // bottom-16 of (R asc-16 ∪ K asc-8): min-layer then bitonic merge-16
#pragma unroll
        for (int t = 0; t < 8; ++t) {
            const uint32_t x = R[8 + t], y = K[7 - t];
            R[8 + t] = x < y ? x : y;
        }
#pragma unroll
        for (int g = 8; g >= 1; g >>= 1)
#pragma unroll
            for (int i = 0; i < 16; ++i)
                if ((i & g) == 0) ceu(R[i], R[i + g]);
    };

    // ---- distributed keep-128 merge over the query's 8 lanes: afterwards
    // position p = h*16+i is fully sorted ascending (union preserved) ----
    auto merge128 = [&]() {
        {
            uint32_t P[16];
#pragma unroll
            for (int i = 0; i < 16; ++i) P[i] = __shfl_xor(R[i], 1, 64);
            const bool lo1 = (h & 1) == 0;
#pragma unroll
            for (int i = 0; i < 16; ++i) {
                const uint32_t o = P[15 - i];
                R[i] = lo1 ? (R[i] < o ? R[i] : o) : (R[i] > o ? R[i] : o);
            }
#pragma unroll
            for (int g = 8; g >= 1; g >>= 1)
#pragma unroll
                for (int i = 0; i < 16; ++i)
                    if ((i & g) == 0) ceu(R[i], R[i + g]);
        }
        {
            uint32_t P[16];
#pragma unroll
            for (int i = 0; i < 16; ++i) P[i] = __shfl_xor(R[i], 3, 64);
            const bool lo2 = (h & 2) == 0;
#pragma unroll
            for (int i = 0; i < 16; ++i) {
                const uint32_t o = P[15 - i];
                R[i] = lo2 ? (R[i] < o ? R[i] : o) : (R[i] > o ? R[i] : o);
            }
#pragma unroll
            for (int i = 0; i < 16; ++i) P[i] = __shfl_xor(R[i], 1, 64);
            const bool lo1 = (h & 1) == 0;
#pragma unroll
            for (int i = 0; i < 16; ++i) {
                const uint32_t o = P[i];
                R[i] = lo1 ? (R[i] < o ? R[i] : o) : (R[i] > o ? R[i] : o);
            }
#pragma unroll
            for (int g = 8; g >= 1; g >>= 1)
#pragma unroll
                for (int i = 0; i < 16; ++i)
                    if ((i & g) == 0) ceu(R[i], R[i + g]);
        }
        {
            uint32_t P[16];
#pragma unroll
            for (int i = 0; i < 16; ++i) P[i] = __shfl_xor(R[i], 7, 64);
            const bool lo4 = (h & 4) == 0;
#pragma unroll
            for (int i = 0; i < 16; ++i) {
                const uint32_t o = P[15 - i];
                R[i] = lo4 ? (R[i] < o ? R[i] : o) : (R[i] > o ? R[i] : o);
            }
#pragma unroll
            for (int i = 0; i < 16; ++i) P[i] = __shfl_xor(R[i], 2, 64);
            const bool lo2 = (h & 2) == 0;
#pragma unroll
            for (int i = 0; i < 16; ++i) {
                const uint32_t o = P[i];
                R[i] = lo2 ? (R[i] < o ? R[i] : o) : (R[i] > o ? R[i] : o);
            }
#pragma unroll
            for (int i = 0; i < 16; ++i) P[i] = __shfl_xor(R[i], 1, 64);
            const bool lo1 = (h & 1) == 0;
#pragma unroll
            for (int i = 0; i < 16; ++i) {
                const uint32_t o = P[i];
                R[i] = lo1 ? (R[i] < o ? R[i] : o) : (R[i] > o ? R[i] : o);
            }
#pragma unroll
            for (int g = 8; g >= 1; g >>= 1)
#pragma unroll
                for (int i = 0; i < 16; ++i)
                    if ((i & g) == 0) ceu(R[i], R[i + g]);
        }
    };

    // ---- seed: 192 contiguous x-neighbors of the query block ----
    const int A = qblk * QPB;
    int seedLo = A - 64;
    if (seedLo < 0) seedLo = 0;
    if (seedLo > LQ - 192) seedLo = LQ - 192;
    scan_group(seedLo); scan_group(seedLo + 64); scan_group(seedLo + 128);
    merge128();

    // exact seed-union 16th key lives at sorted position 15 -> lane h==0
    const uint32_t ub16 = __shfl(R[15], (tid & 63) & ~7, 64);
    uint32_t ubb = (ub16 | 0xFFFu) >> 12;               // f32-bit upper of 16th dist
    ubb = (ubb << 12) | 0xFFFu;                         // bucket upper
    ubb = (ubb > 0xFFFFFFEFu) ? 0xFFFFFFFFu : ubb + 16u;  // +16 ulp margin (verified r4)

    // conservative x-radius: |dx| > rq  =>  fl(dx^2) > ubb
    float rq = __fsqrt_rn(__uint_as_float(ubb));
    rq = __uint_as_float(__float_as_uint(rq) + 8);      // +8 ulp inflation

    float xloN = __fsub_rn(mx, rq);
    float xhiN = __fadd_rn(mx, rq);
    { float t;
      t = __shfl_xor(xloN,  8, 64); xloN = fminf(xloN, t);
      t = __shfl_xor(xloN, 16, 64); xloN = fminf(xloN, t);
      t = __shfl_xor(xloN, 32, 64); xloN = fminf(xloN, t);
      t = __shfl_xor(xhiN,  8, 64); xhiN = fmaxf(xhiN, t);
      t = __shfl_xor(xhiN, 16, 64); xhiN = fmaxf(xhiN, t);
      t = __shfl_xor(xhiN, 32, 64); xhiN = fmaxf(xhiN, t); }

    // binary searches (wave-uniform, LDS broadcast reads)
    int loP = 0, hiP = 0;
#pragma unroll 1
    for (int st = 2048; st >= 1; st >>= 1) {
        if (loP + st <= LQ && xs[loP + st - 1] <  xloN) loP += st;
        if (hiP + st <= LQ && xs[hiP + st - 1] <= xhiN) hiP += st;
    }
    const int loGrp = loP & ~63;
    const int hiGrp = (hiP + 63) & ~63;

    // ---- main scan: static-step loops, seed range skipped ----
    const int e1 = (hiGrp < seedLo) ? hiGrp : seedLo;
#pragma unroll 1
    for (int base = loGrp; base < e1; base += 64) scan_group(base);
    const int sHi = seedLo + 192;
    const int b2 = (loGrp > sHi) ? loGrp : sHi;
#pragma unroll 1
    for (int base = b2; base < hiGrp; base += 64) scan_group(base);

    merge128();

    // lanes 0,1 hold the query's top-32 keys -> publish sorted positions
    if (h < 2) {
#pragma unroll
        for (int i = 0; i < 16; ++i)
            surv[qloc][h * 16 + i] = (u16)(R[i] & 0xFFFu);
    }

    // ---- exact re-rank of the 32 survivors: key = d_bits<<12 | ORIG idx ----
    double kd[4];
#pragma unroll
    for (int s = 0; s < 4; ++s) {
        const int sp = surv[qloc][h * 4 + s];
        const float d = dist2(mx, my, mz, xs[sp], ys[sp], zs[sp]);
        kd[s] = __builtin_bit_cast(double,
                 ((u64)__float_as_uint(d) << 12) | (unsigned)perm_lds[sp]);
    }
    ced(kd[0],kd[1]); ced(kd[2],kd[3]); ced(kd[0],kd[2]); ced(kd[1],kd[3]); ced(kd[1],kd[2]);
    {
        double P[4];
#pragma unroll
        for (int s = 0; s < 4; ++s) P[s] = __shfl_xor(kd[s], 1, 64);
        const bool lo1 = (h & 1) == 0;
#pragma unroll
        for (int s = 0; s < 4; ++s) {
            const double o = P[3 - s];
            kd[s] = lo1 ? __builtin_fmin(kd[s], o) : __builtin_fmax(kd[s], o);
        }
        ced(kd[0],kd[2]); ced(kd[1],kd[3]); ced(kd[0],kd[1]); ced(kd[2],kd[3]);
    }
    {
        double P[4];
#pragma unroll
        for (int s = 0; s < 4; ++s) P[s] = __shfl_xor(kd[s], 3, 64);
        const bool lo2 = (h & 2) == 0;
#pragma unroll
        for (int s = 0; s < 4; ++s) {
            const double o = P[3 - s];
            kd[s] = lo2 ? __builtin_fmin(kd[s], o) : __builtin_fmax(kd[s], o);
        }
#pragma unroll
        for (int s = 0; s < 4; ++s) P[s] = __shfl_xor(kd[s], 1, 64);
        const bool lo1 = (h & 1) == 0;
#pragma unroll
        for (int s = 0; s < 4; ++s) {
            const double o = P[s];
            kd[s] = lo1 ? __builtin_fmin(kd[s], o) : __builtin_fmax(kd[s], o);
        }
        ced(kd[0],kd[2]); ced(kd[1],kd[3]); ced(kd[0],kd[1]); ced(kd[2],kd[3]);
    }
    {
        double P[4];
#pragma unroll
        for (int s = 0; s < 4; ++s) P[s] = __shfl_xor(kd[s], 7, 64);
        const bool lo4 = (h & 4) == 0;
#pragma unroll
        for (int s = 0; s < 4; ++s) {
            const double o = P[3 - s];
            kd[s] = lo4 ? __builtin_fmin(kd[s], o) : __builtin_fmax(kd[s], o);
        }
#pragma unroll
        for (int s = 0; s < 4; ++s) P[s] = __shfl_xor(kd[s], 2, 64);
        const bool lo2 = (h & 2) == 0;
#pragma unroll
        for (int s = 0; s < 4; ++s) {
            const double o = P[s];
            kd[s] = lo2 ? __builtin_fmin(kd[s], o) : __builtin_fmax(kd[s], o);
        }
#pragma unroll
        for (int s = 0; s < 4; ++s) P[s] = __shfl_xor(kd[s], 1, 64);
        const bool lo1 = (h & 1) == 0;
#pragma unroll
        for (int s = 0; s < 4; ++s) {
            const double o = P[s];
            kd[s] = lo1 ? __builtin_fmin(kd[s], o) : __builtin_fmax(kd[s], o);
        }
        ced(kd[0],kd[2]); ced(kd[1],kd[3]); ced(kd[0],kd[1]); ced(kd[2],kd[3]);
    }

    // lanes h<4 hold final top-16 (position h*4+s): epilogue
    const int ql_orig = perm_lds[l];
    const size_t gq = (size_t)b * LQ + (size_t)ql_orig;
    if (h < 4) {
        const float4 f0 = fb[ql_orig * 3 + 0];
        const float4 f1 = fb[ql_orig * 3 + 1];
        const float4 f2 = fb[ql_orig * 3 + 2];
        const float R00 = f0.w, R01 = f1.x, R02 = f1.y;
        const float R10 = f1.z, R11 = f1.w, R12 = f2.x;
        const float R20 = f2.y, R21 = f2.z, R22 = f2.w;
        float e[12];
#pragma unroll
        for (int s = 0; s < 4; ++s) {
            const u64 bits = __builtin_bit_cast(u64, kd[s]);
            const int jo = (int)(bits & 0xFFFu);      // ORIG neighbor index
            nbrs[qloc][h * 4 + s] = jo;
            const int sp = inv_lds[jo];               // coords via sorted pos
            const float dx = xs[sp] - mx;             // delta = nbr - center
            const float dy = ys[sp] - my;
            const float dz = zs[sp] - mz;
            e[s * 3 + 0] = dx * R00 + dy * R10 + dz * R20;
            e[s * 3 + 1] = dx * R01 + dy * R11 + dz * R21;
            e[s * 3 + 2] = dx * R02 + dy * R12 + dz * R22;
        }
        float4* eo = (float4*)(out_e + gq * 48 + h * 12);
        float4 v0 = {e[0], e[1], e[2],  e[3]};
        float4 v1 = {e[4], e[5], e[6],  e[7]};
        float4 v2 = {e[8], e[9], e[10], e[11]};
        eo[0] = v0; eo[1] = v1; eo[2] = v2;
    }

    // ---- fused gather (per wave: its 8 queries x 16 nbrs x 32 float4) ----
    const float4* ab = attr4 + (((size_t)b) << 12) * 32;
    const int lane = tid & 63;
    const int qbase = qblk * QPB + wv * 8;
#pragma unroll 4
    for (int it = 0; it < 64; ++it) {
        const int idx = it * 64 + lane;      // 0..4095
        const int qw  = idx >> 9;            // 0..7 within-wave query
        const int r   = idx & 511;
        const int k   = r >> 5, d4 = r & 31;
        const int nb  = nbrs[wv * 8 + qw][k];
        const int qo  = perm_lds[qbase + qw];
        const float4 v = ab[(size_t)nb * 32 + d4];
        nfloat4 nv = {v.x, v.y, v.z, v.w};
        __builtin_nontemporal_store(nv,
            &outg4[((size_t)b * LQ + (size_t)qo) * 512 + r]);
    }
}

extern "C" void kernel_launch(void* const* d_in, const int* in_sizes, int n_in,
                              void* d_out, int out_size, void* d_ws, size_t ws_size,
                              hipStream_t stream)
{
    const float* frame = (const float*)d_in[0];   // (8,4096,4,3) f32
    const float* attr  = (const float*)d_in[1];   // (8,4096,128) f32
    float* out = (float*)d_out;                   // euclidian ++ gathered

    float* wxp = (float*)d_ws;                    // sorted x   (8*4096)
    float* wyp = wxp + BQ * LQ;                   // sorted y
    float* wzp = wyp + BQ * LQ;                   // sorted z
    int*   wpp = (int*)(wzp + BQ * LQ);           // perm (orig idx)

    sort_kernel<<<BQ, 512, 0, stream>>>((const float4*)frame, wxp, wyp, wzp, wpp);

    nfloat4* outg4 = (nfloat4*)(out + (size_t)BQ * LQ * KNB * 3);
    knn_fused_kernel<<<BQ * BPB, TPB, 0, stream>>>(
        (const float4*)frame, (const float4*)attr, wxp, wyp, wzp, wpp,
        out, outg4);
}

// Round 6
// 329.754 us; speedup vs baseline: 1.2034x; 1.1295x over previous
//
#include <hip/hip_runtime.h>
#include <stdint.h>

typedef unsigned long long u64;
typedef float nfloat4 __attribute__((ext_vector_type(4)));  // native vec for nt-store

#define LQ   4096
#define BQ   8
#define KNB  16
#define TPB  512
#define QPB  64                  // queries per block, 8 lanes each
#define BPB  (LQ / QPB)          // 64 blocks per batch

// u32 compare-exchange (full-rate v_min_u32/v_max_u32)
__device__ __forceinline__ void ceu(uint32_t &a, uint32_t &b) {
    const uint32_t mn = a < b ? a : b;
    const uint32_t mx = a < b ? b : a;
    a = mn; b = mx;
}
// f64 compare-exchange (exact 44-bit keys as positive denormals)
__device__ __forceinline__ void ced(double &a, double &b) {
    const double mn = __builtin_fmin(a, b);
    const double mx = __builtin_fmax(a, b);
    a = mn; b = mx;
}
// bit-exact vs reference: no FMA, sum order (x^2+y^2)+z^2  (re-rank only)
__device__ __forceinline__ float dist2(float mx, float my, float mz,
                                       float px, float py, float pz) {
    const float dx = __fsub_rn(mx, px);
    const float dy = __fsub_rn(my, py);
    const float dz = __fsub_rn(mz, pz);
    return __fadd_rn(__fadd_rn(__fmul_rn(dx, dx), __fmul_rn(dy, dy)),
                     __fmul_rn(dz, dz));
}

// Scan key: (f32 dist bits truncated to top 20) << 12 | j.  Monotone in d, so a
// true top-16 member has <=15 strictly-smaller keys + ~0.01 expected "bucket
// mates" (same 2^-11-relative bucket, smaller j). Keeping per-query top-32
// makes a wrong drop require >=17 mates (prob ~0); the 32 survivors are
// re-ranked exactly with the proven ((u64)d_bits<<12)|j keys.  FMA in the scan
// distance only perturbs keys by ~1-2 ulp << the 4096-ulp truncation bucket;
// this scan-FMA + exact-re-rank construction was harness-verified (r4/r5).

__global__ __launch_bounds__(TPB) void knn_fused_kernel(
    const float4* __restrict__ frame4,   // (B, L, 3) float4 view of (B,L,4,3)
    const float4* __restrict__ attr4,    // (B, L, 32) float4 view of (B,L,128)
    float* __restrict__ out_e,           // (B, L, 16, 3)
    nfloat4* __restrict__ outg4)         // (B, L, 16, 32) float4
{
    __shared__ float4 cpos[LQ];                // 64 KB (w = R00, unused in scan)
    __shared__ unsigned short surv[QPB][32];   // 4 KB  per-query top-32 cand idx
    __shared__ int nbrs[QPB][KNB];             // 4 KB  final neighbor idx
    // total 72 KB -> exactly 2 blocks/CU, grid 512 = 2*256: zero tail

    const int b    = blockIdx.x >> 6;          // 64 blocks per batch
    const int qblk = blockIdx.x & (BPB - 1);
    const int tid  = threadIdx.x;

    const float4* fb = frame4 + (size_t)b * LQ * 3;
    for (int j = tid; j < LQ; j += TPB) cpos[j] = fb[j * 3];
    __syncthreads();   // only barrier: waves are independent afterwards

    const int qloc = tid >> 3;           // 0..63
    const int h    = tid & 7;            // sub-stream within query
    const int l    = qblk * QPB + qloc;
    const float4 me = cpos[l];
    const float mx = me.x, my = me.y, mz = me.z;

    // per-lane running sorted-ascending top-16 of 32-bit keys
    uint32_t R[16];
#pragma unroll
    for (int i = 0; i < 16; ++i) R[i] = 0xFFFFFFFFu;

#pragma unroll 1
    for (int cc = 0; cc < 64; ++cc) {
        uint32_t K[8];
#pragma unroll
        for (int s = 0; s < 8; ++s) {
            const int j = cc * 64 + s * 8 + h;
            const float4 p = cpos[j];            // one ds_read_b128
            const float dx = __fsub_rn(mx, p.x);
            const float dy = __fsub_rn(my, p.y);
            const float dz = __fsub_rn(mz, p.z);
            const float d  = __fmaf_rn(dz, dz, __fmaf_rn(dy, dy, __fmul_rn(dx, dx)));
            K[s] = (__float_as_uint(d) & 0xFFFFF000u) | (unsigned)j;
        }
        // Batcher odd-even mergesort-8 (19 comparators), ascending
        ceu(K[0],K[1]); ceu(K[2],K[3]); ceu(K[4],K[5]); ceu(K[6],K[7]);
        ceu(K[0],K[2]); ceu(K[1],K[3]); ceu(K[4],K[6]); ceu(K[5],K[7]);
        ceu(K[1],K[2]); ceu(K[5],K[6]);
        ceu(K[0],K[4]); ceu(K[1],K[5]); ceu(K[2],K[6]); ceu(K[3],K[7]);
        ceu(K[2],K[4]); ceu(K[3],K[5]);
        ceu(K[1],K[2]); ceu(K[3],K[4]); ceu(K[5],K[6]);
        // bottom-16 of (R asc-16 ∪ K asc-8): min-layer then bitonic merge-16
#pragma unroll
        for (int t = 0; t < 8; ++t) {
            const uint32_t x = R[8 + t], y = K[7 - t];
            R[8 + t] = x < y ? x : y;
        }
#pragma unroll
        for (int g = 8; g >= 1; g >>= 1)
#pragma unroll
            for (int i = 0; i < 16; ++i)
                if ((i & g) == 0) ceu(R[i], R[i + g]);
    }

    // ---- distributed cross-lane merge over the query's 8 lanes, keeping ALL
    // 128 elements: after this, position p = h*16+i is fully sorted ascending.
    {
        uint32_t P[16];
#pragma unroll
        for (int i = 0; i < 16; ++i) P[i] = __shfl_xor(R[i], 1, 64);
        const bool lo1 = (h & 1) == 0;
#pragma unroll
        for (int i = 0; i < 16; ++i) {
            const uint32_t o = P[15 - i];
            R[i] = lo1 ? (R[i] < o ? R[i] : o) : (R[i] > o ? R[i] : o);
        }
#pragma unroll
        for (int g = 8; g >= 1; g >>= 1)
#pragma unroll
            for (int i = 0; i < 16; ++i)
                if ((i & g) == 0) ceu(R[i], R[i + g]);
    }
    {
        uint32_t P[16];
#pragma unroll
        for (int i = 0; i < 16; ++i) P[i] = __shfl_xor(R[i], 3, 64);
        const bool lo2 = (h & 2) == 0;
#pragma unroll
        for (int i = 0; i < 16; ++i) {
            const uint32_t o = P[15 - i];
            R[i] = lo2 ? (R[i] < o ? R[i] : o) : (R[i] > o ? R[i] : o);
        }
#pragma unroll
        for (int i = 0; i < 16; ++i) P[i] = __shfl_xor(R[i], 1, 64);
        const bool lo1 = (h & 1) == 0;
#pragma unroll
        for (int i = 0; i < 16; ++i) {
            const uint32_t o = P[i];
            R[i] = lo1 ? (R[i] < o ? R[i] : o) : (R[i] > o ? R[i] : o);
        }
#pragma unroll
        for (int g = 8; g >= 1; g >>= 1)
#pragma unroll
            for (int i = 0; i < 16; ++i)
                if ((i & g) == 0) ceu(R[i], R[i + g]);
    }
    {
        uint32_t P[16];
#pragma unroll
        for (int i = 0; i < 16; ++i) P[i] = __shfl_xor(R[i], 7, 64);
        const bool lo4 = (h & 4) == 0;
#pragma unroll
        for (int i = 0; i < 16; ++i) {
            const uint32_t o = P[15 - i];
            R[i] = lo4 ? (R[i] < o ? R[i] : o) : (R[i] > o ? R[i] : o);
        }
#pragma unroll
        for (int i = 0; i < 16; ++i) P[i] = __shfl_xor(R[i], 2, 64);
        const bool lo2 = (h & 2) == 0;
#pragma unroll
        for (int i = 0; i < 16; ++i) {
            const uint32_t o = P[i];
            R[i] = lo2 ? (R[i] < o ? R[i] : o) : (R[i] > o ? R[i] : o);
        }
#pragma unroll
        for (int i = 0; i < 16; ++i) P[i] = __shfl_xor(R[i], 1, 64);
        const bool lo1 = (h & 1) == 0;
#pragma unroll
        for (int i = 0; i < 16; ++i) {
            const uint32_t o = P[i];
            R[i] = lo1 ? (R[i] < o ? R[i] : o) : (R[i] > o ? R[i] : o);
        }
#pragma unroll
        for (int g = 8; g >= 1; g >>= 1)
#pragma unroll
            for (int i = 0; i < 16; ++i)
                if ((i & g) == 0) ceu(R[i], R[i + g]);
    }

    // lanes 0,1 hold the query's top-32 keys -> publish candidate indices
    if (h < 2) {
#pragma unroll
        for (int i = 0; i < 16; ++i)
            surv[qloc][h * 16 + i] = (unsigned short)(R[i] & 0xFFFu);
    }

    // ---- exact re-rank of the 32 survivors with 44-bit keys (f64 denormals).
    // 4 keys per lane; distributed bitonic merge to sorted-32 over 8 lanes.
    double kd[4];
#pragma unroll
    for (int s = 0; s < 4; ++s) {
        const int j = surv[qloc][h * 4 + s];
        const float4 p = cpos[j];
        const float d = dist2(mx, my, mz, p.x, p.y, p.z);
        kd[s] = __builtin_bit_cast(double,
                 ((u64)__float_as_uint(d) << 12) | (unsigned)j);
    }
    ced(kd[0],kd[1]); ced(kd[2],kd[3]); ced(kd[0],kd[2]); ced(kd[1],kd[3]); ced(kd[1],kd[2]);
    {
        double P[4];
#pragma unroll
        for (int s = 0; s < 4; ++s) P[s] = __shfl_xor(kd[s], 1, 64);
        const bool lo1 = (h & 1) == 0;
#pragma unroll
        for (int s = 0; s < 4; ++s) {
            const double o = P[3 - s];
            kd[s] = lo1 ? __builtin_fmin(kd[s], o) : __builtin_fmax(kd[s], o);
        }
        ced(kd[0],kd[2]); ced(kd[1],kd[3]); ced(kd[0],kd[1]); ced(kd[2],kd[3]);
    }
    {
        double P[4];
#pragma unroll
        for (int s = 0; s < 4; ++s) P[s] = __shfl_xor(kd[s], 3, 64);
        const bool lo2 = (h & 2) == 0;
#pragma unroll
        for (int s = 0; s < 4; ++s) {
            const double o = P[3 - s];
            kd[s] = lo2 ? __builtin_fmin(kd[s], o) : __builtin_fmax(kd[s], o);
        }
#pragma unroll
        for (int s = 0; s < 4; ++s) P[s] = __shfl_xor(kd[s], 1, 64);
        const bool lo1 = (h & 1) == 0;
#pragma unroll
        for (int s = 0; s < 4; ++s) {
            const double o = P[s];
            kd[s] = lo1 ? __builtin_fmin(kd[s], o) : __builtin_fmax(kd[s], o);
        }
        ced(kd[0],kd[2]); ced(kd[1],kd[3]); ced(kd[0],kd[1]); ced(kd[2],kd[3]);
    }
    {
        double P[4];
#pragma unroll
        for (int s = 0; s < 4; ++s) P[s] = __shfl_xor(kd[s], 7, 64);
        const bool lo4 = (h & 4) == 0;
#pragma unroll
        for (int s = 0; s < 4; ++s) {
            const double o = P[3 - s];
            kd[s] = lo4 ? __builtin_fmin(kd[s], o) : __builtin_fmax(kd[s], o);
        }
#pragma unroll
        for (int s = 0; s < 4; ++s) P[s] = __shfl_xor(kd[s], 2, 64);
        const bool lo2 = (h & 2) == 0;
#pragma unroll
        for (int s = 0; s < 4; ++s) {
            const double o = P[s];
            kd[s] = lo2 ? __builtin_fmin(kd[s], o) : __builtin_fmax(kd[s], o);
        }
#pragma unroll
        for (int s = 0; s < 4; ++s) P[s] = __shfl_xor(kd[s], 1, 64);
        const bool lo1 = (h & 1) == 0;
#pragma unroll
        for (int s = 0; s < 4; ++s) {
            const double o = P[s];
            kd[s] = lo1 ? __builtin_fmin(kd[s], o) : __builtin_fmax(kd[s], o);
        }
        ced(kd[0],kd[2]); ced(kd[1],kd[3]); ced(kd[0],kd[1]); ced(kd[2],kd[3]);
    }

    // lanes h<4 hold final top-16 (position h*4+s): epilogue
    const size_t gq = (size_t)b * LQ + l;
    if (h < 4) {
        const float4 f1 = fb[l * 3 + 1];
        const float4 f2 = fb[l * 3 + 2];
        const float R00 = me.w, R01 = f1.x, R02 = f1.y;
        const float R10 = f1.z, R11 = f1.w, R12 = f2.x;
        const float R20 = f2.y, R21 = f2.z, R22 = f2.w;
        float e[12];
#pragma unroll
        for (int s = 0; s < 4; ++s) {
            const u64 bits = __builtin_bit_cast(u64, kd[s]);
            const int j = (int)(bits & 0xFFFu);
            nbrs[qloc][h * 4 + s] = j;
            const float4 p = cpos[j];
            const float dx = p.x - mx;        // delta = nbr_center - center
            const float dy = p.y - my;
            const float dz = p.z - mz;
            e[s * 3 + 0] = dx * R00 + dy * R10 + dz * R20;
            e[s * 3 + 1] = dx * R01 + dy * R11 + dz * R21;
            e[s * 3 + 2] = dx * R02 + dy * R12 + dz * R22;
        }
        float4* eo = (float4*)(out_e + gq * 48 + h * 12);
        float4 v0 = {e[0], e[1], e[2],  e[3]};
        float4 v1 = {e[4], e[5], e[6],  e[7]};
        float4 v2 = {e[8], e[9], e[10], e[11]};
        eo[0] = v0; eo[1] = v1; eo[2] = v2;
    }

    // ---- fused gather (per wave: its 8 queries x 16 nbrs x 32 float4) ----
    const float4* ab = attr4 + (((size_t)b) << 12) * 32;
    const int wv = tid >> 6, lane = tid & 63;    // wv = 0..7
    const size_t obase = ((size_t)b * LQ + (size_t)qblk * QPB + (size_t)wv * 8) * 512;
#pragma unroll 4
    for (int it = 0; it < 64; ++it) {
        const int idx = it * 64 + lane;      // 0..4095
        const int qw  = idx >> 9;            // 0..7 within-wave query
        const int r   = idx & 511;
        const int k   = r >> 5, d4 = r & 31;
        const int nb  = nbrs[wv * 8 + qw][k];
        const float4 v = ab[(size_t)nb * 32 + d4];
        nfloat4 nv = {v.x, v.y, v.z, v.w};
        __builtin_nontemporal_store(nv, &outg4[obase + idx]);
    }
}

extern "C" void kernel_launch(void* const* d_in, const int* in_sizes, int n_in,
                              void* d_out, int out_size, void* d_ws, size_t ws_size,
                              hipStream_t stream)
{
    const float* frame = (const float*)d_in[0];   // (8,4096,4,3) f32
    const float* attr  = (const float*)d_in[1];   // (8,4096,128) f32
    float* out = (float*)d_out;                   // euclidian ++ gathered

    nfloat4* outg4 = (nfloat4*)(out + (size_t)BQ * LQ * KNB * 3);
    knn_fused_kernel<<<BQ * BPB, TPB, 0, stream>>>(
        (const float4*)frame, (const float4*)attr, out, outg4);
}